// Round 6
// baseline (555.547 us; speedup 1.0000x reference)
//
#include <hip/hip_runtime.h>
#include <hip/hip_bf16.h>
#include <hip/hip_fp16.h>
#include <stdint.h>

// Problem constants (fixed by the reference)
#define NN   50000
#define RR   50
#define BB   30
#define DIN  64
#define EE   1000000
#define KTOT (BB*DIN + DIN)   // 1984 = 62*32
#define NBW  16               // nodes per workgroup; 50000 = 3125*16 exactly
#define ROWE (KTOT + 8)       // padded LDS row: 1992 elems (3984 B)
#define CPAD 32               // comp row padded 30 -> 32 halves (64 B)
#define EPAD (EE + 4*NN + 16) // ep2 entries incl. per-node 4-alignment ghosts

typedef __attribute__((ext_vector_type(8))) short short8;
typedef __attribute__((ext_vector_type(4))) float floatx4;

#define RFL(x) __builtin_amdgcn_readfirstlane(x)

// ---------------- preprocessing: counting sort of edges by dst ----------------

__global__ void k_hist(const int* __restrict__ dst, const int* __restrict__ et,
                       int* __restrict__ cnt) {
    int e = blockIdx.x * 256 + threadIdx.x;
    if (e < EE) {
        int d = dst[e], r = et[e];
        atomicAdd(&cnt[d * RR + r], 1);
    }
}

// derive dcount from cnt rows; PAD each node's segment to a multiple of 4
// (ghost slots stay all-zero from the ep2 memset -> exact no-op edges, and
// every chunk becomes two aligned int4 record loads, no masking).
__global__ void k_scan1(const int* __restrict__ cnt, int* __restrict__ dcount,
                        int* __restrict__ doff, int* __restrict__ bsum) {
    __shared__ int sh[256];
    int t = threadIdx.x;
    int i = blockIdx.x * 256 + t;
    int vp = 0;
    if (i < NN) {
        const int* c = cnt + (size_t)i * RR;
        int v = 0;
#pragma unroll
        for (int r = 0; r < RR; ++r) v += c[r];
        vp = (v + 3) & ~3;                 // padded count
        dcount[i] = vp;
    }
    sh[t] = vp;
    __syncthreads();
    for (int s = 1; s < 256; s <<= 1) {
        int add = (t >= s) ? sh[t - s] : 0;
        __syncthreads();
        sh[t] += add;
        __syncthreads();
    }
    int incl = sh[t];
    if (i < NN) doff[i] = incl - vp;
    if (t == 255) bsum[blockIdx.x] = incl;
}

__global__ void k_scan2(int* __restrict__ bsum, int nbv) {
    __shared__ int sh[256];
    int t = threadIdx.x;
    int v = (t < nbv) ? bsum[t] : 0;
    sh[t] = v;
    __syncthreads();
    for (int s = 1; s < 256; s <<= 1) {
        int add = (t >= s) ? sh[t - s] : 0;
        __syncthreads();
        sh[t] += add;
        __syncthreads();
    }
    if (t < nbv) bsum[t] = sh[t] - v;
}

__global__ void k_scan3(int* __restrict__ doff, const int* __restrict__ bsum) {
    int i = blockIdx.x * 256 + threadIdx.x;
    if (i < NN) doff[i] += bsum[blockIdx.x];
}

// records: .x = src | (rel<<16)  (src<65536, rel<50), .y = bits of a = 1/cnt(d,r)
__global__ void k_scatter(const int* __restrict__ src, const int* __restrict__ dst,
                          const int* __restrict__ et, const int* __restrict__ cnt,
                          const int* __restrict__ doff, int* __restrict__ cursor,
                          int2* __restrict__ ep2) {
    int e = blockIdx.x * 256 + threadIdx.x;
    if (e < EE) {
        int d = dst[e], r = et[e], s = src[e];
        int p = doff[d] + atomicAdd(&cursor[d], 1);
        float a = 1.0f / (float)cnt[d * RR + r];
        ep2[p] = make_int2(s | (r << 16), __float_as_int(a));
    }
}

// ---------------- degree counting-sort (descending) for wave balance ----------
// LDS-aggregated two-level histograms (<=256 global atomics per block).

__global__ void k_deghist(const int* __restrict__ dcount, int* __restrict__ dbin) {
    __shared__ int lh[256];
    int t = threadIdx.x;
    int i = blockIdx.x * 256 + t;
    lh[t] = 0;
    __syncthreads();
    if (i < NN) {
        int d = dcount[i]; d = (d > 255) ? 255 : d;
        atomicAdd(&lh[255 - d], 1);          // LDS atomic
    }
    __syncthreads();
    if (lh[t]) atomicAdd(&dbin[t], lh[t]);   // 1 global atomic per bin per block
}

__global__ void k_degscan(int* __restrict__ dbin) {   // exclusive scan of 256
    __shared__ int sh[256];
    int t = threadIdx.x;
    int v = dbin[t];
    sh[t] = v;
    __syncthreads();
    for (int s = 1; s < 256; s <<= 1) {
        int add = (t >= s) ? sh[t - s] : 0;
        __syncthreads();
        sh[t] += add;
        __syncthreads();
    }
    dbin[t] = sh[t] - v;
}

__global__ void k_degscatter(const int* __restrict__ dcount, const int* __restrict__ dbin,
                             int* __restrict__ dcur, int* __restrict__ order) {
    __shared__ int lh[256], lbase[256];
    int t = threadIdx.x;
    int i = blockIdx.x * 256 + t;
    lh[t] = 0;
    __syncthreads();
    int b = 0, lpos = 0;
    if (i < NN) {
        int d = dcount[i]; d = (d > 255) ? 255 : d;
        b = 255 - d;
        lpos = atomicAdd(&lh[b], 1);         // LDS atomic
    }
    __syncthreads();
    lbase[t] = lh[t] ? atomicAdd(&dcur[t], lh[t]) : 0;  // 1 global atomic per bin
    __syncthreads();
    if (i < NN) order[dbin[b] + lbase[b] + lpos] = i;
}

__global__ void k_cast_x(const float* __restrict__ x, __hip_bfloat16* __restrict__ h) {
    int i = blockIdx.x * 256 + threadIdx.x;
    if (i < NN * DIN) h[i] = __float2bfloat16(x[i]);
}

// all 3 layers' comp [R,30] fp32 -> padded f16 [3][R,32]
__global__ void k_prep_comp3(const float* __restrict__ c0, const float* __restrict__ c1,
                             const float* __restrict__ c2, __half* __restrict__ cp) {
    int idx = blockIdx.x * 256 + threadIdx.x;
    if (idx < 3 * RR * CPAD) {
        int l = idx / (RR * CPAD);
        int rem = idx - l * (RR * CPAD);
        int r = rem / CPAD, i = rem - r * CPAD;
        const float* c = (l == 0) ? c0 : (l == 1) ? c1 : c2;
        cp[idx] = (i < BB) ? __float2half(c[r * BB + i]) : __float2half(0.f);
    }
}

// all 3 layers' transposed bf16 weights:
// wt rows [0,64): layer0; [64,128): layer1; [128,144): layer2 (dout=8, 16 padded rows)
__global__ void k_prep_w3(const float* __restrict__ b0, const float* __restrict__ r0,
                          const float* __restrict__ b1, const float* __restrict__ r1,
                          const float* __restrict__ b2, const float* __restrict__ r2,
                          short* __restrict__ wt) {
    int idx = blockIdx.x * 256 + threadIdx.x;
    if (idx >= 144 * KTOT) return;
    int row = idx / KTOT, k = idx - row * KTOT;
    const float* bs; const float* rt; int o, dout;
    if (row < 64)       { bs = b0; rt = r0; o = row;        dout = 64; }
    else if (row < 128) { bs = b1; rt = r1; o = row - 64;   dout = 64; }
    else                { bs = b2; rt = r2; o = row - 128;  dout = 8;  }
    float v = 0.f;
    if (o < dout)
        v = (k < BB * DIN) ? bs[k * dout + o] : rt[(k - BB * DIN) * dout + o];
    __hip_bfloat16 hb = __float2bfloat16(v);
    wt[idx] = *reinterpret_cast<const short*>(&hb);
}

// ---------------- fused per-layer kernel ----------------
// 1024 threads = 16 waves, 2 blocks/CU (LDS-capped) -> 32 waves/CU.
// R5 post-mortem: record loads (uniform addr) compiled to SMEM; comp-row
// s_loads forced lgkmcnt(0) per edge, draining the just-issued record load
// (L2/HBM latency exposed EVERY iteration). Fix:
//  * records -> VMEM domain: base address de-uniformed via ds_bpermute so the
//    compiler emits global_load_dwordx4 with counted vmcnt (rides with gathers).
//  * comp rows: all 16 s_loads of a chunk hoisted & batched at iteration top;
//    one lgkmcnt wait per chunk (~scalar-L1 hit), covered by RFL/addr VALU.
// Pipeline distances (proven R5): records +2 iters, gathers +3 iters.
// f16 packed accumulation (v_pk_fma_f16); 4-aligned ghost-padded segments
// (a=0 ghosts -> exact no-op, no masking/tail); degree-sorted node order.
// Phase 2 unchanged: MFMA 16x16x32 bf16 over K=1984.

struct RecS { int x0, a0i, x1, a1i, x2, a2i, x3, a3i; };   // wave-uniform scalars

// VMEM record load (per-lane ptr from de-uniformed base4V; 2x dwordx4)
#define LOADREC4(u, VA, VB) do {                                                \
    const int _u = ((u) < nch) ? (u) : (nch - 1);                               \
    const int4* _p = ep4 + (base4V + 2 * _u);                                   \
    VA = _p[0]; VB = _p[1];                                                     \
} while (0)

#define RFLREC(VA, VB, S) do {                                                  \
    S.x0 = RFL((VA).x); S.a0i = RFL((VA).y);                                    \
    S.x1 = RFL((VA).z); S.a1i = RFL((VA).w);                                    \
    S.x2 = RFL((VB).x); S.a2i = RFL((VB).y);                                    \
    S.x3 = RFL((VB).z); S.a3i = RFL((VB).w);                                    \
} while (0)

#define GATH1(sx) ((unsigned)xin16[((sx) & 0xFFFF) * DIN + lane])

// FMA with pre-loaded comp row (4x int4 in SGPRs)
#define EDGE_FMA_PRE(M0, M1, M2, M3, _ai, _g) do {                              \
    const float _xvf = __uint_as_float((unsigned)(_g) << 16) * __int_as_float(_ai); \
    const __half _xh = __float2half(_xvf);                                      \
    const __half2 _xv2 = __halves2half2(_xh, _xh);                              \
    const __half2* _p0 = reinterpret_cast<const __half2*>(&(M0));               \
    const __half2* _p1 = reinterpret_cast<const __half2*>(&(M1));               \
    const __half2* _p2 = reinterpret_cast<const __half2*>(&(M2));               \
    const __half2* _p3 = reinterpret_cast<const __half2*>(&(M3));               \
    acc[0]  = __hfma2(_p0[0], _xv2, acc[0]);                                    \
    acc[1]  = __hfma2(_p0[1], _xv2, acc[1]);                                    \
    acc[2]  = __hfma2(_p0[2], _xv2, acc[2]);                                    \
    acc[3]  = __hfma2(_p0[3], _xv2, acc[3]);                                    \
    acc[4]  = __hfma2(_p1[0], _xv2, acc[4]);                                    \
    acc[5]  = __hfma2(_p1[1], _xv2, acc[5]);                                    \
    acc[6]  = __hfma2(_p1[2], _xv2, acc[6]);                                    \
    acc[7]  = __hfma2(_p1[3], _xv2, acc[7]);                                    \
    acc[8]  = __hfma2(_p2[0], _xv2, acc[8]);                                    \
    acc[9]  = __hfma2(_p2[1], _xv2, acc[9]);                                    \
    acc[10] = __hfma2(_p2[2], _xv2, acc[10]);                                   \
    acc[11] = __hfma2(_p2[3], _xv2, acc[11]);                                   \
    acc[12] = __hfma2(_p3[0], _xv2, acc[12]);                                   \
    acc[13] = __hfma2(_p3[1], _xv2, acc[13]);                                   \
    acc[14] = __hfma2(_p3[2], _xv2, acc[14]);                                   \
    acc[15] = __hfma2(_p3[3], _xv2, acc[15]);                                   \
} while (0)

// one pipeline iteration:
//   top: RFL records(t+3); batch s_load comp rows for chunk t;
//        issue gathers(t+3); issue record load(t+5);
//   then FMA chunk t (gathers from t-3, comp just batched); rotate.
#define ITER(tt, VA, VB) do {                                                   \
    RecS s3; RFLREC(VA, VB, s3);                                                \
    const int4* _cp0 = (const int4*)(compH + ((unsigned)s0.x0 >> 16) * CPAD);   \
    const int4* _cp1 = (const int4*)(compH + ((unsigned)s0.x1 >> 16) * CPAD);   \
    const int4* _cp2 = (const int4*)(compH + ((unsigned)s0.x2 >> 16) * CPAD);   \
    const int4* _cp3 = (const int4*)(compH + ((unsigned)s0.x3 >> 16) * CPAD);   \
    int4 _e0a = _cp0[0], _e0b = _cp0[1], _e0c = _cp0[2], _e0d = _cp0[3];        \
    int4 _e1a = _cp1[0], _e1b = _cp1[1], _e1c = _cp1[2], _e1d = _cp1[3];        \
    int4 _e2a = _cp2[0], _e2b = _cp2[1], _e2c = _cp2[2], _e2d = _cp2[3];        \
    int4 _e3a = _cp3[0], _e3b = _cp3[1], _e3c = _cp3[2], _e3d = _cp3[3];        \
    unsigned w0 = GATH1(s3.x0), w1 = GATH1(s3.x1);                              \
    unsigned w2 = GATH1(s3.x2), w3 = GATH1(s3.x3);                              \
    LOADREC4((tt) + 5, VA, VB);                                                 \
    EDGE_FMA_PRE(_e0a, _e0b, _e0c, _e0d, s0.a0i, g0);                           \
    EDGE_FMA_PRE(_e1a, _e1b, _e1c, _e1d, s0.a1i, g1);                           \
    EDGE_FMA_PRE(_e2a, _e2b, _e2c, _e2d, s0.a2i, g2);                           \
    EDGE_FMA_PRE(_e3a, _e3b, _e3c, _e3d, s0.a3i, g3);                           \
    s0 = s1; s1 = s2; s2 = s3;                                                  \
    g0 = h0; g1 = h1; g2 = h2; g3 = h3;                                         \
    h0 = i0; h1 = i1; h2 = i2; h3 = i3;                                         \
    i0 = w0; i1 = w1; i2 = w2; i3 = w3;                                         \
} while (0)

template <int DOUT, bool RELU>
__global__ __launch_bounds__(1024, 8)
void k_fused(const __hip_bfloat16* __restrict__ xin,
             const int2* __restrict__ ep2,
             const int* __restrict__ doff, const int* __restrict__ dcount,
             const int* __restrict__ order,
             const __half* __restrict__ compH,   // [R, 32] f16 padded
             const short* __restrict__ Wt,       // [DPAD][KTOT] bf16 (transposed)
             const float* __restrict__ bias,     // [DOUT]
             void* __restrict__ outp) {
    __shared__ __align__(16) char smem_raw[NBW * ROWE * 2];   // 63744 B
    auto t_tile = reinterpret_cast<__hip_bfloat16(*)[ROWE]>(smem_raw);
    const unsigned short* xin16 = reinterpret_cast<const unsigned short*>(xin);
    const int tid  = threadIdx.x;
    const int lane = tid & 63;
    const int wv   = RFL(tid >> 6);          // 0..15
    const int node0 = blockIdx.x * NBW;

    // ---- phase 1: one node per wave, deep pipelined 4-edge chunks ----
    {
        const int j = wv;
        const int n = RFL(order[node0 + j]);
        __half2 acc[16];
#pragma unroll
        for (int u = 0; u < 16; ++u)
            acc[u] = __halves2half2(__float2half(0.f), __float2half(0.f));
        const int beg = RFL(doff[n]);
        const int nch = RFL(dcount[n]) >> 2;   // padded count / 4, no tail
        // self row: issue early, consume at epilogue
        const unsigned selfb = (unsigned)xin16[n * DIN + lane];

        if (nch > 0) {
            const int4* ep4 = reinterpret_cast<const int4*>(ep2);
            // de-uniformed base index: value == beg>>1 in every lane, but the
            // compiler can't prove it -> record loads become VMEM (vmcnt),
            // decoupled from the comp-row SMEM (lgkmcnt) domain.
            const int base4V = __builtin_amdgcn_ds_bpermute(0, beg >> 1);
            int4 vaA, vbA, vaB, vbB;
            RecS s0, s1, s2;
            // prologue: fill 3 gather stages + 2 record stages
            LOADREC4(0, vaA, vbA);
            LOADREC4(1, vaB, vbB);
            RFLREC(vaA, vbA, s0);
            unsigned g0 = GATH1(s0.x0), g1 = GATH1(s0.x1);
            unsigned g2 = GATH1(s0.x2), g3 = GATH1(s0.x3);
            LOADREC4(2, vaA, vbA);
            RFLREC(vaB, vbB, s1);
            unsigned h0 = GATH1(s1.x0), h1 = GATH1(s1.x1);
            unsigned h2 = GATH1(s1.x2), h3 = GATH1(s1.x3);
            LOADREC4(3, vaB, vbB);
            RFLREC(vaA, vbA, s2);
            unsigned i0 = GATH1(s2.x0), i1 = GATH1(s2.x1);
            unsigned i2 = GATH1(s2.x2), i3 = GATH1(s2.x3);
            LOADREC4(4, vaA, vbA);
            // stages now: A = chunk 4 (in flight), B = chunk 3 (in flight)
            int t = 0;
            for (; t + 2 <= nch; t += 2) {
                ITER(t,     vaB, vbB);   // consumes chunk t+3, loads t+5 into B
                ITER(t + 1, vaA, vbA);   // consumes chunk t+4, loads t+6 into A
            }
            if (t < nch) ITER(t, vaB, vbB);
        }
#pragma unroll
        for (int b = 0; b < BB; ++b) {
            const float v = (b & 1) ? __high2float(acc[b >> 1]) : __low2float(acc[b >> 1]);
            t_tile[j][b * DIN + lane] = __float2bfloat16(v);
        }
        t_tile[j][BB * DIN + lane] =
            __float2bfloat16(__uint_as_float(selfb << 16));
    }
    __syncthreads();

    // ---- phase 2: MFMA 16x16x32 bf16, K = 1984 (62 steps) over 16 waves ----
    const int m = lane & 15;
    const int q = lane >> 4;
    int kk0, nsteps, col_base, kpart;
    if (DOUT == 64) {
        kpart = wv >> 2;                 // 0..3
        col_base = (wv & 3) * 16;
        kk0    = (kpart <= 1) ? kpart * 16 : (kpart == 2 ? 32 : 47);
        nsteps = (kpart <= 1) ? 16 : 15;
    } else {
        kpart = wv;                      // 0..15
        col_base = 0;
        kk0    = (kpart < 14) ? kpart * 4 : (kpart == 14 ? 56 : 59);
        nsteps = (kpart < 14) ? 4 : 3;
    }
    const __hip_bfloat16* arow = &t_tile[m][q * 8];
    const short* brow = Wt + (size_t)(col_base + m) * KTOT + q * 8;

    floatx4 acc0 = {0.f, 0.f, 0.f, 0.f};
    floatx4 acc1 = {0.f, 0.f, 0.f, 0.f};
    int s = 0;
    for (; s + 2 <= nsteps; s += 2) {
        const int kk = kk0 + s;
        short8 a0 = *reinterpret_cast<const short8*>(arow + kk * 32);
        short8 b0 = *reinterpret_cast<const short8*>(brow + kk * 32);
        short8 a1 = *reinterpret_cast<const short8*>(arow + (kk + 1) * 32);
        short8 b1 = *reinterpret_cast<const short8*>(brow + (kk + 1) * 32);
        acc0 = __builtin_amdgcn_mfma_f32_16x16x32_bf16(a0, b0, acc0, 0, 0, 0);
        acc1 = __builtin_amdgcn_mfma_f32_16x16x32_bf16(a1, b1, acc1, 0, 0, 0);
    }
    if (s < nsteps) {
        const int kk = kk0 + s;
        short8 a0 = *reinterpret_cast<const short8*>(arow + kk * 32);
        short8 b0 = *reinterpret_cast<const short8*>(brow + kk * 32);
        acc0 = __builtin_amdgcn_mfma_f32_16x16x32_bf16(a0, b0, acc0, 0, 0, 0);
    }
    floatx4 P = acc0 + acc1;

    __syncthreads();                       // all t_tile reads done
    float* red = (float*)smem_raw;         // reuse LDS; stride-6 layout

    if (DOUT == 64) {
        // 4 K-parts per col group; parts 1..3 write, part 0 reduces
        if (kpart > 0) {
            const int slot = (wv & 3) * 3 + (kpart - 1);   // 0..11
            const int off = (slot * 64 + lane) * 6;
            red[off] = P[0]; red[off + 1] = P[1]; red[off + 2] = P[2]; red[off + 3] = P[3];
        }
        __syncthreads();
        if (kpart == 0) {
#pragma unroll
            for (int t = 0; t < 3; ++t) {
                const int off = (((wv & 3) * 3 + t) * 64 + lane) * 6;
                P[0] += red[off]; P[1] += red[off + 1];
                P[2] += red[off + 2]; P[3] += red[off + 3];
            }
            const int o = col_base + m;
            const float bi = bias[o];
#pragma unroll
            for (int r = 0; r < 4; ++r) {
                const int n = order[node0 + q * 4 + r];
                float v = P[r] + bi;
                if (RELU) {
                    v = fmaxf(v, 0.f);
                    reinterpret_cast<__hip_bfloat16*>(outp)[(size_t)n * DOUT + o] =
                        __float2bfloat16(v);
                } else {
                    reinterpret_cast<float*>(outp)[(size_t)n * DOUT + o] = v;
                }
            }
        }
    } else {
        if (kpart > 0) {
            const int off = ((kpart - 1) * 64 + lane) * 6;
            red[off] = P[0]; red[off + 1] = P[1]; red[off + 2] = P[2]; red[off + 3] = P[3];
        }
        __syncthreads();
        if (kpart == 0) {
#pragma unroll
            for (int w = 0; w < 15; ++w) {
                const int off = (w * 64 + lane) * 6;
                P[0] += red[off]; P[1] += red[off + 1];
                P[2] += red[off + 2]; P[3] += red[off + 3];
            }
            if (m < DOUT) {
                const int o = m;
                const float bi = bias[o];
#pragma unroll
                for (int r = 0; r < 4; ++r) {
                    const int n = order[node0 + q * 4 + r];
                    reinterpret_cast<float*>(outp)[(size_t)n * DOUT + o] = P[r] + bi;
                }
            }
        }
    }
}

// ---------------- log_softmax over C=8 ----------------
__global__ void k_lsm(const float* __restrict__ pre, float* __restrict__ out) {
    int n = blockIdx.x * 256 + threadIdx.x;
    if (n < NN) {
        float v[8];
        float mx = -1e30f;
#pragma unroll
        for (int c = 0; c < 8; ++c) { v[c] = pre[n * 8 + c]; mx = fmaxf(mx, v[c]); }
        float s = 0.f;
#pragma unroll
        for (int c = 0; c < 8; ++c) s += expf(v[c] - mx);
        float ls = logf(s);
#pragma unroll
        for (int c = 0; c < 8; ++c) out[n * 8 + c] = v[c] - mx - ls;
    }
}

// ---------------- launch ----------------
extern "C" void kernel_launch(void* const* d_in, const int* in_sizes, int n_in,
                              void* d_out, int out_size, void* d_ws, size_t ws_size,
                              hipStream_t stream) {
    const float* x     = (const float*)d_in[0];
    const int*   eidx  = (const int*)d_in[1];
    const int*   etype = (const int*)d_in[2];
    const float* bases0 = (const float*)d_in[3];
    const float* comp0  = (const float*)d_in[4];
    const float* root0  = (const float*)d_in[5];
    const float* bias0  = (const float*)d_in[6];
    const float* bases1 = (const float*)d_in[7];
    const float* comp1  = (const float*)d_in[8];
    const float* root1  = (const float*)d_in[9];
    const float* bias1  = (const float*)d_in[10];
    const float* bases2 = (const float*)d_in[11];
    const float* comp2  = (const float*)d_in[12];
    const float* root2  = (const float*)d_in[13];
    const float* bias2  = (const float*)d_in[14];
    const int* srcp = eidx;
    const int* dstp = eidx + EE;

    char* p = (char*)d_ws;
    auto carve = [&](size_t bytes) -> char* {
        char* r = p;
        p += (bytes + 255) & ~(size_t)255;
        return r;
    };
    int*  cnt    = (int*)carve((size_t)NN * RR * sizeof(int));   // 10 MB
    int*  dcount = (int*)carve((size_t)NN * sizeof(int));
    int*  cursor = (int*)carve((size_t)NN * sizeof(int));
    int*  doff   = (int*)carve((size_t)NN * sizeof(int));
    int*  bsum   = (int*)carve(256 * sizeof(int));
    int*  dbin   = (int*)carve(256 * sizeof(int));
    int*  dcur   = (int*)carve(256 * sizeof(int));
    int*  order  = (int*)carve((size_t)NN * sizeof(int));
    int2* ep2    = (int2*)carve((size_t)EPAD * sizeof(int2));    // ~9.6 MB
    __hip_bfloat16* h0 = (__hip_bfloat16*)carve((size_t)NN * DIN * 2);
    __hip_bfloat16* h1 = (__hip_bfloat16*)carve((size_t)NN * DIN * 2);
    __hip_bfloat16* h2 = (__hip_bfloat16*)carve((size_t)NN * DIN * 2);
    float* pre = (float*)carve((size_t)NN * 8 * sizeof(float));
    short* wtA = (short*)carve((size_t)144 * KTOT * sizeof(short));  // 3 layers stacked
    __half* cpA = (__half*)carve((size_t)3 * RR * CPAD * sizeof(__half));

    // cnt, dcount, cursor are adjacent in the carve order -> one memset
    hipMemsetAsync(cnt, 0, (size_t)NN * (RR + 2) * sizeof(int) + 512, stream);
    // dbin, dcur adjacent (each carved to 1024 B)
    hipMemsetAsync(dbin, 0, 2048, stream);
    // ghost record slots must be zero (a=0 -> exact no-op edges)
    hipMemsetAsync(ep2, 0, (size_t)EPAD * sizeof(int2), stream);

    const int EB = (EE + 255) / 256;   // 3907
    const int NB = (NN + 255) / 256;   // 196
    k_hist<<<EB, 256, 0, stream>>>(dstp, etype, cnt);
    k_scan1<<<NB, 256, 0, stream>>>(cnt, dcount, doff, bsum);
    k_scan2<<<1, 256, 0, stream>>>(bsum, NB);
    k_scan3<<<NB, 256, 0, stream>>>(doff, bsum);
    k_scatter<<<EB, 256, 0, stream>>>(srcp, dstp, etype, cnt, doff, cursor, ep2);
    k_deghist<<<NB, 256, 0, stream>>>(dcount, dbin);
    k_degscan<<<1, 256, 0, stream>>>(dbin);
    k_degscatter<<<NB, 256, 0, stream>>>(dcount, dbin, dcur, order);
    k_cast_x<<<(NN * DIN + 255) / 256, 256, 0, stream>>>(x, h0);
    k_prep_comp3<<<(3 * RR * CPAD + 255) / 256, 256, 0, stream>>>(comp0, comp1, comp2, cpA);
    k_prep_w3<<<(144 * KTOT + 255) / 256, 256, 0, stream>>>(bases0, root0, bases1, root1,
                                                            bases2, root2, wtA);

    short* wt0 = wtA;
    short* wt1 = wtA + (size_t)64 * KTOT;
    short* wt2 = wtA + (size_t)128 * KTOT;
    __half* cp0 = cpA;
    __half* cp1 = cpA + RR * CPAD;
    __half* cp2 = cpA + 2 * RR * CPAD;

    const int NF = NN / NBW;   // 3125 (exact)
    k_fused<64, true ><<<NF, 1024, 0, stream>>>(h0, ep2, doff, dcount, order, cp0, wt0, bias0, (void*)h1);
    k_fused<64, true ><<<NF, 1024, 0, stream>>>(h1, ep2, doff, dcount, order, cp1, wt1, bias1, (void*)h2);
    k_fused<8,  false><<<NF, 1024, 0, stream>>>(h2, ep2, doff, dcount, order, cp2, wt2, bias2, (void*)pre);
    k_lsm<<<NB, 256, 0, stream>>>(pre, (float*)d_out);
}